// Round 8
// baseline (428.785 us; speedup 1.0000x reference)
//
#include <hip/hip_runtime.h>
#include <hip/hip_cooperative_groups.h>
#include <math.h>

namespace cg = cooperative_groups;

#define N_NODES 10000
#define WPR 320            // padded bitmap words/row (5*64 covers exactly)
#define CAP 96             // neighbor capacity (deg ~ mean 32, sd 5.7)
#define NTHR 256
#define BN_EPS 1e-5f
#define DEG_EPS 1e-8f
#define SHARDS 32
#define FPSCALE 4194304.0  // 2^22 fixed-point scale for deterministic BN sums

struct Params {
    const float* x; const int* e; int E;
    const float* W0; const float* b0; const float* g0; const float* be0;
    const float* W1; const float* b1; const float* g1; const float* be1;
    const float* Wo; const float* bo; const float* Wa; const float* ba;
    float* out;
    unsigned* bm; int* nbr; int* cnt; float* dinv; float* xs;
    float* hA; float* hB; float* hBs;
    unsigned long long* acc;   // [4][32][SHARDS] int64 fixed-point BN sums
};

__global__ void __launch_bounds__(NTHR) fused_gnn(Params p) {
    cg::grid_group grid = cg::this_grid();
    const int tid  = threadIdx.x;
    const int ntot = gridDim.x * NTHR;
    const int nwav = ntot >> 6;
    const int g    = blockIdx.x * NTHR + tid;
    const int lane = tid & 63;
    const int gw   = g >> 6;
    const int shard = blockIdx.x & (SHARDS - 1);

    __shared__ float ls[256], lq[256];
    __shared__ float sc[32], sh[32];

    // ---------- P0: clear bitmap + zero BN accumulators ----------
    {
        uint4* bm4 = (uint4*)p.bm;
        const int n16 = N_NODES * WPR / 4;           // 800000
        for (int t = g; t < n16; t += ntot) bm4[t] = make_uint4(0u, 0u, 0u, 0u);
        if (g < 4 * 32 * SHARDS) p.acc[g] = 0ull;
    }
    grid.sync();

    // ---------- P1: scatter edges (SET semantics, idempotent atomicOr) ----------
    for (int t = g; t < p.E; t += ntot) {
        int s = p.e[t];
        int d = p.e[p.E + t];
        atomicOr(&p.bm[(size_t)s * WPR + (d >> 5)], 1u << (d & 31));
    }
    grid.sync();

    // ---------- P2: bitmap -> CSR + dinv + prescaled x ----------
    for (int i = gw; i < N_NODES; i += nwav) {
        const unsigned* row = p.bm + (size_t)i * WPR;
        int* outl = p.nbr + (size_t)i * CAP;
        int running = 0;
        #pragma unroll
        for (int step = 0; step < 5; ++step) {        // 5*64 == WPR
            unsigned bits = row[step * 64 + lane];
            int n = __popc(bits);
            int off = n;                               // inclusive prefix over 64 lanes
            #pragma unroll
            for (int d = 1; d < 64; d <<= 1) {
                int v = __shfl_up(off, d);
                if (lane >= d) off += v;
            }
            int total = __shfl(off, 63);
            int slot = running + off - n;              // exclusive prefix
            int w = step * 64 + lane;
            while (bits) {
                int b = __ffs(bits) - 1; bits &= bits - 1;
                if (slot < CAP) outl[slot] = (w << 5) + b;
                slot++;
            }
            running += total;
        }
        float di = rsqrtf((float)(running + 1) + DEG_EPS);  // +1 from identity
        if (lane == 0) { p.cnt[i] = running < CAP ? running : CAP; p.dinv[i] = di; }
        if (lane < 6) p.xs[(size_t)i * 6 + lane] = di * p.x[(size_t)i * 6 + lane];
    }
    grid.sync();

    // ---------- P3: agg1 (dim 6) + GEMM W0 + BN1 sums ----------
    {
        float ps = 0.f, pq = 0.f;
        for (int i = gw; i < N_NODES; i += nwav) {
            int c = p.cnt[i];
            const int* lst = p.nbr + (size_t)i * CAP;
            float acc[6] = {0.f, 0.f, 0.f, 0.f, 0.f, 0.f};
            for (int k = lane; k < c; k += 64) {
                int j = lst[k];
                const float* xj = p.xs + (size_t)j * 6;
                #pragma unroll
                for (int d = 0; d < 6; ++d) acc[d] += xj[d];
            }
            #pragma unroll
            for (int d = 0; d < 6; ++d) {
                #pragma unroll
                for (int off = 32; off; off >>= 1) acc[d] += __shfl_xor(acc[d], off);
            }
            float di = p.dinv[i];
            if (lane < 32) {
                float s = p.b0[lane];
                #pragma unroll
                for (int d = 0; d < 6; ++d)
                    s += (acc[d] + p.xs[(size_t)i * 6 + d]) * di * p.W0[d * 32 + lane];
                p.hA[(size_t)i * 32 + lane] = s;
                ps += s; pq += s * s;
            }
        }
        ls[tid] = ps; lq[tid] = pq;
        __syncthreads();
        if (tid < 32) {
            float s = 0.f, q = 0.f;
            #pragma unroll
            for (int k = 0; k < 8; ++k) { s += ls[k * 32 + tid]; q += lq[k * 32 + tid]; }
            // deterministic fixed-point accumulation (order-independent)
            atomicAdd(&p.acc[(0 * 32 + tid) * SHARDS + shard],
                      (unsigned long long)(long long)__double2ll_rn((double)s * FPSCALE));
            atomicAdd(&p.acc[(1 * 32 + tid) * SHARDS + shard],
                      (unsigned long long)(long long)__double2ll_rn((double)q * FPSCALE));
        }
    }
    grid.sync();

    // ---------- P4: BN1 scale/shift (redundant per block) + apply + ReLU + prescale ----------
    {
        if (tid < 32) {
            long long Si = 0, Qi = 0;
            #pragma unroll
            for (int s2 = 0; s2 < SHARDS; ++s2) {
                Si += (long long)p.acc[(0 * 32 + tid) * SHARDS + s2];
                Qi += (long long)p.acc[(1 * 32 + tid) * SHARDS + s2];
            }
            float mu = (float)((double)Si / FPSCALE / (double)N_NODES);
            float e2 = (float)((double)Qi / FPSCALE / (double)N_NODES);
            float var = e2 - mu * mu;                  // biased
            float rstd = rsqrtf(var + BN_EPS);
            float scale = p.g0[tid] * rstd;
            sc[tid] = scale; sh[tid] = p.be0[tid] - mu * scale;
        }
        __syncthreads();
        for (int idx = g; idx < N_NODES * 32; idx += ntot) {
            int f = idx & 31;
            float v = p.hA[idx] * sc[f] + sh[f];
            v = v > 0.f ? v : 0.f;
            p.hB[idx] = v;                             // residual input
            p.hBs[idx] = v * p.dinv[idx >> 5];         // prescaled for agg2
        }
    }
    grid.sync();

    // ---------- P5: agg2 (dim 32, wave-uniform ILP) + GEMM W1 + BN2 sums ----------
    {
        const int f = lane & 31;
        const int half = lane >> 5;
        float ps = 0.f, pq = 0.f;
        for (int i = gw; i < N_NODES; i += nwav) {
            int c = p.cnt[i];
            const int* lst = p.nbr + (size_t)i * CAP;
            int idxA = lst[lane];                      // coalesced 256B load
            int cF = c < 64 ? c : 64;                  // wave-uniform
            float acc = 0.f;
            int kb = 0;
            for (; kb + 8 <= cF; kb += 8) {            // uniform trip count
                int j0 = __shfl(idxA, kb + half);
                int j1 = __shfl(idxA, kb + half + 2);
                int j2 = __shfl(idxA, kb + half + 4);
                int j3 = __shfl(idxA, kb + half + 6);
                float v0 = p.hBs[(size_t)j0 * 32 + f];
                float v1 = p.hBs[(size_t)j1 * 32 + f];
                float v2 = p.hBs[(size_t)j2 * 32 + f];
                float v3 = p.hBs[(size_t)j3 * 32 + f];
                acc += v0 + v1 + v2 + v3;
            }
            for (int k = kb + half; k < c; k += 2)     // tail: no cross-lane ops
                acc += p.hBs[(size_t)lst[k] * 32 + f];
            acc += __shfl_xor(acc, 32);                // combine halves
            float t = (acc + p.hBs[(size_t)i * 32 + f]) * p.dinv[i];
            float part = 0.f;
            int fbase = half * 16;
            #pragma unroll
            for (int kk = 0; kk < 16; ++kk)
                part += __shfl(t, fbase + kk) * p.W1[(fbase + kk) * 32 + f];
            part += __shfl_xor(part, 32);
            if (lane < 32) {
                float sv = p.b1[f] + part;
                p.hA[(size_t)i * 32 + f] = sv;
                ps += sv; pq += sv * sv;
            }
        }
        ls[tid] = ps; lq[tid] = pq;
        __syncthreads();
        if (tid < 32) {
            float s = 0.f, q = 0.f;
            #pragma unroll
            for (int k = 0; k < 8; ++k) { s += ls[k * 32 + tid]; q += lq[k * 32 + tid]; }
            atomicAdd(&p.acc[(2 * 32 + tid) * SHARDS + shard],
                      (unsigned long long)(long long)__double2ll_rn((double)s * FPSCALE));
            atomicAdd(&p.acc[(3 * 32 + tid) * SHARDS + shard],
                      (unsigned long long)(long long)__double2ll_rn((double)q * FPSCALE));
        }
    }
    grid.sync();

    // ---------- P6: BN2 + ReLU + residual + heads ----------
    {
        if (tid < 32) {
            long long Si = 0, Qi = 0;
            #pragma unroll
            for (int s2 = 0; s2 < SHARDS; ++s2) {
                Si += (long long)p.acc[(2 * 32 + tid) * SHARDS + s2];
                Qi += (long long)p.acc[(3 * 32 + tid) * SHARDS + s2];
            }
            float mu = (float)((double)Si / FPSCALE / (double)N_NODES);
            float e2 = (float)((double)Qi / FPSCALE / (double)N_NODES);
            float var = e2 - mu * mu;
            float rstd = rsqrtf(var + BN_EPS);
            float scale = p.g1[tid] * rstd;
            sc[tid] = scale; sh[tid] = p.be1[tid] - mu * scale;
        }
        __syncthreads();
        const int l = tid & 31;
        for (int r = g >> 5; r < N_NODES; r += ntot >> 5) {
            int idx = r * 32 + l;
            float v = p.hA[idx] * sc[l] + sh[l];
            v = v > 0.f ? v : 0.f;
            v += p.hB[idx];                            // residual -> final h
            float q0 = v * p.Wo[l * 2 + 0];
            float q1 = v * p.Wo[l * 2 + 1];
            float qa = v * p.Wa[l];
            #pragma unroll
            for (int off = 16; off; off >>= 1) {
                q0 += __shfl_xor(q0, off);
                q1 += __shfl_xor(q1, off);
                qa += __shfl_xor(qa, off);
            }
            if (l == 0) {
                p.out[(size_t)r * 2 + 0] = q0 + p.bo[0];
                p.out[(size_t)r * 2 + 1] = q1 + p.bo[1];
                p.out[2 * N_NODES + r] = 1.f / (1.f + expf(-(qa + p.ba[0])));
            }
        }
    }
}

extern "C" void kernel_launch(void* const* d_in, const int* in_sizes, int n_in,
                              void* d_out, int out_size, void* d_ws, size_t ws_size,
                              hipStream_t stream) {
    Params prm;
    prm.x   = (const float*)d_in[0];
    prm.e   = (const int*)d_in[1];
    prm.E   = in_sizes[1] / 2;
    prm.W0  = (const float*)d_in[2];
    prm.b0  = (const float*)d_in[3];
    prm.g0  = (const float*)d_in[4];
    prm.be0 = (const float*)d_in[5];
    prm.W1  = (const float*)d_in[6];
    prm.b1  = (const float*)d_in[7];
    prm.g1  = (const float*)d_in[8];
    prm.be1 = (const float*)d_in[9];
    prm.Wo  = (const float*)d_in[10];
    prm.bo  = (const float*)d_in[11];
    prm.Wa  = (const float*)d_in[12];
    prm.ba  = (const float*)d_in[13];
    prm.out = (float*)d_out;

    char* ws = (char*)d_ws;
    size_t off = 0;
    auto take = [&](size_t bytes) { char* q = ws + off; off += (bytes + 255) & ~(size_t)255; return q; };
    prm.bm   = (unsigned*)take((size_t)N_NODES * WPR * 4);   // 12.8 MB
    prm.nbr  = (int*)take((size_t)N_NODES * CAP * 4);        // 3.84 MB
    prm.cnt  = (int*)take((size_t)N_NODES * 4);
    prm.dinv = (float*)take((size_t)N_NODES * 4);
    prm.xs   = (float*)take((size_t)N_NODES * 6 * 4);
    prm.hA   = (float*)take((size_t)N_NODES * 32 * 4);
    prm.hB   = (float*)take((size_t)N_NODES * 32 * 4);
    prm.hBs  = (float*)take((size_t)N_NODES * 32 * 4);
    prm.acc  = (unsigned long long*)take((size_t)4 * 32 * SHARDS * 8);  // 32 KB

    // Full-occupancy cooperative grid: all blocks must be co-resident.
    int maxPerCU = 0;
    hipOccupancyMaxActiveBlocksPerMultiprocessor(&maxPerCU, (const void*)fused_gnn, NTHR, 0);
    int nblk = maxPerCU * 256;                       // 256 CUs on MI355X
    if (nblk < 256) nblk = 256;
    if (nblk > 2048) nblk = 2048;

    void* args[] = { &prm };
    hipLaunchCooperativeKernel((const void*)fused_gnn, dim3(nblk), dim3(NTHR),
                               args, 0, stream);
}

// Round 9
// 125.831 us; speedup vs baseline: 3.4076x; 3.4076x over previous
//
#include <hip/hip_runtime.h>
#include <math.h>

#define N_NODES 10000
#define WPR 320            // padded bitmap words/row
#define CAP 96             // neighbor capacity (deg ~ mean 32, sd 5.7)
#define BN_EPS 1e-5f
#define DEG_EPS 1e-8f
#define SHARDS 32

// ---------------- K1: clear bitmap + cnt + BN accumulators (contiguous) ----------------
__global__ void __launch_bounds__(256) clear_ws(uint4* __restrict__ p, int n16) {
    int t = blockIdx.x * blockDim.x + threadIdx.x;
    if (t < n16) p[t] = make_uint4(0u, 0u, 0u, 0u);
}

// ---------------- K2: scatter + dedup (atomicOr old value) + CSR append ----------------
__global__ void __launch_bounds__(256) scatter_csr(const int* __restrict__ e, int E,
                                                   unsigned* __restrict__ bm,
                                                   int* __restrict__ cnt,
                                                   int* __restrict__ nbr) {
    int t = blockIdx.x * blockDim.x + threadIdx.x;
    if (t < E) {
        int s = e[t];
        int d = e[E + t];
        unsigned bit = 1u << (d & 31);
        unsigned old = atomicOr(&bm[(size_t)s * WPR + (d >> 5)], bit);
        if (!(old & bit)) {                       // exactly one owner per unique edge
            int slot = atomicAdd(&cnt[s], 1);
            if (slot < CAP) nbr[(size_t)s * CAP + slot] = d;
        }
    }
}

// ---------------- K3: agg1 (dim6, dinv on the fly) + GEMM W0 + BN1 shard-atomics ----------------
__global__ void __launch_bounds__(256) agg1_gemm_bn(const int* __restrict__ nbr,
                                                    const int* __restrict__ cnt,
                                                    const float* __restrict__ x,
                                                    const float* __restrict__ W0,
                                                    const float* __restrict__ b0,
                                                    float* __restrict__ dinv,
                                                    float* __restrict__ h1,
                                                    float* __restrict__ acc) {
    int tid = threadIdx.x;
    int lane = tid & 63;
    int i = blockIdx.x * 4 + (tid >> 6);          // one row per wave, 2500 blocks
    float ps = 0.f, pq = 0.f;
    if (i < N_NODES) {
        int ctrue = cnt[i];
        int c = ctrue < CAP ? ctrue : CAP;
        float di = rsqrtf((float)(ctrue + 1) + DEG_EPS);
        if (lane == 0) dinv[i] = di;
        const int* lst = nbr + (size_t)i * CAP;
        float a[6] = {0.f, 0.f, 0.f, 0.f, 0.f, 0.f};
        for (int k = lane; k < c; k += 64) {
            int j = lst[k];
            float dj = rsqrtf((float)(cnt[j] + 1) + DEG_EPS);
            const float* xj = x + (size_t)j * 6;
            #pragma unroll
            for (int d = 0; d < 6; ++d) a[d] += dj * xj[d];
        }
        #pragma unroll
        for (int d = 0; d < 6; ++d) {
            #pragma unroll
            for (int off = 32; off; off >>= 1) a[d] += __shfl_xor(a[d], off);
        }
        if (lane < 32) {
            float s = b0[lane];
            #pragma unroll
            for (int d = 0; d < 6; ++d)
                s += (a[d] + di * x[(size_t)i * 6 + d]) * di * W0[d * 32 + lane];
            h1[(size_t)i * 32 + lane] = s;
            ps = s; pq = s * s;
        }
    }
    __shared__ float ls[256], lq[256];
    ls[tid] = ps; lq[tid] = pq;
    __syncthreads();
    if (tid < 32) {
        float s = 0.f, q = 0.f;
        #pragma unroll
        for (int k = 0; k < 8; ++k) { s += ls[k * 32 + tid]; q += lq[k * 32 + tid]; }
        int shard = blockIdx.x & (SHARDS - 1);
        atomicAdd(&acc[(0 * 32 + tid) * SHARDS + shard], s);
        atomicAdd(&acc[(1 * 32 + tid) * SHARDS + shard], q);
    }
}

// ---------------- K4: agg2 (BN1 applied on the fly) + GEMM W1 + BN2 shard-atomics ----------------
__global__ void __launch_bounds__(256) agg2_gemm_bn(const int* __restrict__ nbr,
                                                    const int* __restrict__ cnt,
                                                    const float* __restrict__ dinv,
                                                    const float* __restrict__ h1,
                                                    const float* __restrict__ g0,
                                                    const float* __restrict__ be0,
                                                    const float* __restrict__ W1,
                                                    const float* __restrict__ b1,
                                                    float* __restrict__ h2,
                                                    float* __restrict__ acc) {
    __shared__ float sc[32], sh[32];
    int tid = threadIdx.x;
    if (tid < 32) {                                // BN1 affine from shard sums
        float S = 0.f, Q = 0.f;
        #pragma unroll
        for (int s2 = 0; s2 < SHARDS; ++s2) {
            S += acc[(0 * 32 + tid) * SHARDS + s2];
            Q += acc[(1 * 32 + tid) * SHARDS + s2];
        }
        float mu = S / (float)N_NODES;
        float var = Q / (float)N_NODES - mu * mu;  // biased
        float rstd = rsqrtf(var + BN_EPS);
        float scale = g0[tid] * rstd;
        sc[tid] = scale; sh[tid] = be0[tid] - mu * scale;
    }
    __syncthreads();
    int lane = tid & 63;
    int f = lane & 31, half = lane >> 5;
    float scf = sc[f], shf = sh[f];
    int i = blockIdx.x * 4 + (tid >> 6);           // one row per wave
    float ps = 0.f, pq = 0.f;
    if (i < N_NODES) {
        int ctrue = cnt[i];
        int c = ctrue < CAP ? ctrue : CAP;
        const int* lst = nbr + (size_t)i * CAP;
        int idxA = lst[lane];                      // coalesced (garbage beyond c unused)
        int cF = c < 64 ? c : 64;                  // wave-uniform
        float a = 0.f;
        int kb = 0;
        for (; kb + 8 <= cF; kb += 8) {            // uniform trip, shfl sources active
            int j0 = __shfl(idxA, kb + half);
            int j1 = __shfl(idxA, kb + half + 2);
            int j2 = __shfl(idxA, kb + half + 4);
            int j3 = __shfl(idxA, kb + half + 6);
            float v0 = fmaxf(h1[(size_t)j0 * 32 + f] * scf + shf, 0.f) * dinv[j0];
            float v1 = fmaxf(h1[(size_t)j1 * 32 + f] * scf + shf, 0.f) * dinv[j1];
            float v2 = fmaxf(h1[(size_t)j2 * 32 + f] * scf + shf, 0.f) * dinv[j2];
            float v3 = fmaxf(h1[(size_t)j3 * 32 + f] * scf + shf, 0.f) * dinv[j3];
            a += v0 + v1 + v2 + v3;
        }
        for (int k = kb + half; k < c; k += 2) {   // tail: direct loads only
            int j = lst[k];
            a += fmaxf(h1[(size_t)j * 32 + f] * scf + shf, 0.f) * dinv[j];
        }
        a += __shfl_xor(a, 32);                    // combine halves
        float di = dinv[i];
        float vi = fmaxf(h1[(size_t)i * 32 + f] * scf + shf, 0.f) * di;  // self (identity)
        float t = (a + vi) * di;
        float part = 0.f;
        int fbase = half * 16;
        #pragma unroll
        for (int kk = 0; kk < 16; ++kk)
            part += __shfl(t, fbase + kk) * W1[(fbase + kk) * 32 + f];
        part += __shfl_xor(part, 32);
        if (lane < 32) {
            float sv = b1[f] + part;
            h2[(size_t)i * 32 + f] = sv;
            ps = sv; pq = sv * sv;
        }
    }
    __shared__ float ls[256], lq[256];
    ls[tid] = ps; lq[tid] = pq;
    __syncthreads();
    if (tid < 32) {
        float s = 0.f, q = 0.f;
        #pragma unroll
        for (int k = 0; k < 8; ++k) { s += ls[k * 32 + tid]; q += lq[k * 32 + tid]; }
        int shard = blockIdx.x & (SHARDS - 1);
        atomicAdd(&acc[(2 * 32 + tid) * SHARDS + shard], s);
        atomicAdd(&acc[(3 * 32 + tid) * SHARDS + shard], q);
    }
}

// ---------------- K5: BN1+BN2 affines + ReLU + residual + heads ----------------
__global__ void __launch_bounds__(256) final_fused(const float* __restrict__ h1,
                                                   const float* __restrict__ h2,
                                                   const float* __restrict__ acc,
                                                   const float* __restrict__ g0,
                                                   const float* __restrict__ be0,
                                                   const float* __restrict__ g1,
                                                   const float* __restrict__ be1,
                                                   const float* __restrict__ Wo,
                                                   const float* __restrict__ bo,
                                                   const float* __restrict__ Wa,
                                                   const float* __restrict__ ba,
                                                   float* __restrict__ out) {
    __shared__ float sc1[32], sh1[32], sc2[32], sh2[32];
    int tid = threadIdx.x;
    if (tid < 64) {                                // tid<32: BN1, tid>=32: BN2
        int ff = tid & 31;
        int base = (tid < 32) ? 0 : 2;
        float S = 0.f, Q = 0.f;
        #pragma unroll
        for (int s2 = 0; s2 < SHARDS; ++s2) {
            S += acc[((base + 0) * 32 + ff) * SHARDS + s2];
            Q += acc[((base + 1) * 32 + ff) * SHARDS + s2];
        }
        float mu = S / (float)N_NODES;
        float var = Q / (float)N_NODES - mu * mu;
        float rstd = rsqrtf(var + BN_EPS);
        if (tid < 32) {
            float scale = g0[ff] * rstd;
            sc1[ff] = scale; sh1[ff] = be0[ff] - mu * scale;
        } else {
            float scale = g1[ff] * rstd;
            sc2[ff] = scale; sh2[ff] = be1[ff] - mu * scale;
        }
    }
    __syncthreads();
    const int l = tid & 31;
    for (int r = (blockIdx.x * 256 + tid) >> 5; r < N_NODES; r += 1250 * 8) {
        int idx = r * 32 + l;
        float v1 = fmaxf(h1[idx] * sc1[l] + sh1[l], 0.f);   // hB (residual)
        float v2 = fmaxf(h2[idx] * sc2[l] + sh2[l], 0.f);   // h_new
        float v = v1 + v2;                                   // final h
        float q0 = v * Wo[l * 2 + 0];
        float q1 = v * Wo[l * 2 + 1];
        float qa = v * Wa[l];
        #pragma unroll
        for (int off = 16; off; off >>= 1) {
            q0 += __shfl_xor(q0, off);
            q1 += __shfl_xor(q1, off);
            qa += __shfl_xor(qa, off);
        }
        if (l == 0) {
            out[(size_t)r * 2 + 0] = q0 + bo[0];
            out[(size_t)r * 2 + 1] = q1 + bo[1];
            out[2 * N_NODES + r] = 1.f / (1.f + expf(-(qa + ba[0])));
        }
    }
}

extern "C" void kernel_launch(void* const* d_in, const int* in_sizes, int n_in,
                              void* d_out, int out_size, void* d_ws, size_t ws_size,
                              hipStream_t stream) {
    const float* x   = (const float*)d_in[0];
    const int*  eidx = (const int*)d_in[1];
    const int E = in_sizes[1] / 2;
    const float* W0 = (const float*)d_in[2];
    const float* b0 = (const float*)d_in[3];
    const float* g0 = (const float*)d_in[4];
    const float* be0= (const float*)d_in[5];
    const float* W1 = (const float*)d_in[6];
    const float* b1 = (const float*)d_in[7];
    const float* g1 = (const float*)d_in[8];
    const float* be1= (const float*)d_in[9];
    const float* Wo = (const float*)d_in[10];
    const float* bo = (const float*)d_in[11];
    const float* Wa = (const float*)d_in[12];
    const float* ba = (const float*)d_in[13];
    float* out = (float*)d_out;

    char* ws = (char*)d_ws;
    size_t off = 0;
    auto take = [&](size_t bytes) { char* q = ws + off; off += (bytes + 255) & ~(size_t)255; return q; };
    // bm, cnt, acc contiguous so ONE clear kernel covers all three (pads included)
    unsigned* bm  = (unsigned*)take((size_t)N_NODES * WPR * 4);    // 12,800,000 B
    int* cnt      = (int*)take((size_t)N_NODES * 4);               // 40,192 B padded
    float* acc    = (float*)take((size_t)4 * 32 * SHARDS * 4);     // 16,384 B
    const size_t clear_bytes = (size_t)N_NODES * WPR * 4 + 40192 + 16384;  // 12,856,576
    int* nbr      = (int*)take((size_t)N_NODES * CAP * 4);         // 3.84 MB
    float* dinv   = (float*)take((size_t)N_NODES * 4);
    float* h1     = (float*)take((size_t)N_NODES * 32 * 4);        // layer-1 pre-BN
    float* h2     = (float*)take((size_t)N_NODES * 32 * 4);        // layer-2 pre-BN

    const int n16 = (int)(clear_bytes / 16);                       // 803,536
    clear_ws<<<(n16 + 255) / 256, 256, 0, stream>>>((uint4*)bm, n16);
    scatter_csr<<<(E + 255) / 256, 256, 0, stream>>>(eidx, E, bm, cnt, nbr);
    agg1_gemm_bn<<<2500, 256, 0, stream>>>(nbr, cnt, x, W0, b0, dinv, h1, acc);
    agg2_gemm_bn<<<2500, 256, 0, stream>>>(nbr, cnt, dinv, h1, g0, be0, W1, b1, h2, acc);
    final_fused<<<1250, 256, 0, stream>>>(h1, h2, acc, g0, be0, g1, be1,
                                          Wo, bo, Wa, ba, out);
}

// Round 10
// 124.120 us; speedup vs baseline: 3.4546x; 1.0138x over previous
//
#include <hip/hip_runtime.h>
#include <math.h>

#define N_NODES 10000
#define WPR 320            // padded bitmap words/row
#define CAP 96             // neighbor capacity (deg ~ mean 32, sd 5.7)
#define BN_EPS 1e-5f
#define DEG_EPS 1e-8f
#define SHARDS 32

// ---------------- K1: clear bitmap + cnt + BN accumulators (one contiguous range) ----------------
__global__ void __launch_bounds__(256) clear_ws(uint4* __restrict__ p, int n16) {
    int t = blockIdx.x * blockDim.x + threadIdx.x;
    if (t < n16) p[t] = make_uint4(0u, 0u, 0u, 0u);
}

// ---------------- K2: scatter + dedup (atomicOr old value) + CSR append ----------------
__global__ void __launch_bounds__(256) scatter_csr(const int* __restrict__ e, int E,
                                                   unsigned* __restrict__ bm,
                                                   int* __restrict__ cnt,
                                                   int* __restrict__ nbr) {
    int t = blockIdx.x * blockDim.x + threadIdx.x;
    if (t < E) {
        int s = e[t];
        int d = e[E + t];
        unsigned bit = 1u << (d & 31);
        unsigned old = atomicOr(&bm[(size_t)s * WPR + (d >> 5)], bit);
        if (!(old & bit)) {                       // exactly one owner per unique edge
            int slot = atomicAdd(&cnt[s], 1);
            if (slot < CAP) nbr[(size_t)s * CAP + slot] = d;
        }
    }
}

// ---------------- K3: agg1 (dim6, dinv on the fly — single parallel round) + GEMM W0 + BN1 shards ----------------
__global__ void __launch_bounds__(256) agg1_gemm_bn(const int* __restrict__ nbr,
                                                    const int* __restrict__ cnt,
                                                    const float* __restrict__ x,
                                                    const float* __restrict__ W0,
                                                    const float* __restrict__ b0,
                                                    float* __restrict__ dinv,
                                                    float* __restrict__ h1,
                                                    float* __restrict__ acc) {
    int tid = threadIdx.x;
    int lane = tid & 63;
    int i = blockIdx.x * 4 + (tid >> 6);          // one row per wave, 2500 blocks
    float ps = 0.f, pq = 0.f;
    {
        int ctrue = cnt[i];
        int c = ctrue < CAP ? ctrue : CAP;
        float di = rsqrtf((float)(ctrue + 1) + DEG_EPS);
        if (lane == 0) dinv[i] = di;
        const int* lst = nbr + (size_t)i * CAP;
        float a[6] = {0.f, 0.f, 0.f, 0.f, 0.f, 0.f};
        for (int k = lane; k < c; k += 64) {      // c<=96: at most 2 rounds, usually 1
            int j = lst[k];
            float dj = rsqrtf((float)(cnt[j] + 1) + DEG_EPS);
            const float* xj = x + (size_t)j * 6;
            #pragma unroll
            for (int d = 0; d < 6; ++d) a[d] += dj * xj[d];
        }
        #pragma unroll
        for (int d = 0; d < 6; ++d) {
            #pragma unroll
            for (int off = 32; off; off >>= 1) a[d] += __shfl_xor(a[d], off);
        }
        if (lane < 32) {
            float s = b0[lane];
            #pragma unroll
            for (int d = 0; d < 6; ++d)
                s += (a[d] + di * x[(size_t)i * 6 + d]) * di * W0[d * 32 + lane];
            h1[(size_t)i * 32 + lane] = s;
            ps = s; pq = s * s;
        }
    }
    __shared__ float ls[256], lq[256];
    ls[tid] = ps; lq[tid] = pq;
    __syncthreads();
    if (tid < 32) {
        float s = 0.f, q = 0.f;
        #pragma unroll
        for (int k = 0; k < 8; ++k) { s += ls[k * 32 + tid]; q += lq[k * 32 + tid]; }
        int shard = blockIdx.x & (SHARDS - 1);
        atomicAdd(&acc[(0 * 32 + tid) * SHARDS + shard], s);
        atomicAdd(&acc[(1 * 32 + tid) * SHARDS + shard], q);
    }
}

// ---------------- K4: BN1 affine + apply + ReLU -> hB; prescale -> hBs ----------------
__global__ void __launch_bounds__(256) bn1_apply(const float* __restrict__ h1,
                                                 const float* __restrict__ acc,
                                                 const float* __restrict__ g0,
                                                 const float* __restrict__ be0,
                                                 const float* __restrict__ dinv,
                                                 float* __restrict__ hB,
                                                 float* __restrict__ hBs) {
    __shared__ float sc[32], sh[32];
    int tid = threadIdx.x;
    if (tid < 32) {
        float S = 0.f, Q = 0.f;
        #pragma unroll
        for (int s2 = 0; s2 < SHARDS; ++s2) {
            S += acc[(0 * 32 + tid) * SHARDS + s2];
            Q += acc[(1 * 32 + tid) * SHARDS + s2];
        }
        float mu = S / (float)N_NODES;
        float var = Q / (float)N_NODES - mu * mu;  // biased
        float rstd = rsqrtf(var + BN_EPS);
        float scale = g0[tid] * rstd;
        sc[tid] = scale; sh[tid] = be0[tid] - mu * scale;
    }
    __syncthreads();
    for (int idx = blockIdx.x * 256 + tid; idx < N_NODES * 32; idx += 640 * 256) {
        int f = idx & 31;
        float v = fmaxf(h1[idx] * sc[f] + sh[f], 0.f);
        hB[idx] = v;                               // residual input
        hBs[idx] = v * dinv[idx >> 5];             // prescaled for agg2
    }
}

// ---------------- K5: agg2 (prescaled hBs, wave-uniform ILP-4) + GEMM W1 + BN2 shards ----------------
__global__ void __launch_bounds__(256) agg2_gemm_bn(const int* __restrict__ nbr,
                                                    const int* __restrict__ cnt,
                                                    const float* __restrict__ dinv,
                                                    const float* __restrict__ hBs,
                                                    const float* __restrict__ W1,
                                                    const float* __restrict__ b1,
                                                    float* __restrict__ h2,
                                                    float* __restrict__ acc) {
    int tid = threadIdx.x;
    int lane = tid & 63;
    int f = lane & 31, half = lane >> 5;
    int i = blockIdx.x * 4 + (tid >> 6);           // one row per wave, 2500 blocks
    float ps = 0.f, pq = 0.f;
    {
        int ctrue = cnt[i];
        int c = ctrue < CAP ? ctrue : CAP;
        const int* lst = nbr + (size_t)i * CAP;
        int idxA = lst[lane];                      // coalesced 256B load
        int cF = c < 64 ? c : 64;                  // wave-uniform
        float a = 0.f;
        int kb = 0;
        for (; kb + 8 <= cF; kb += 8) {            // uniform trip, shfl sources active
            int j0 = __shfl(idxA, kb + half);
            int j1 = __shfl(idxA, kb + half + 2);
            int j2 = __shfl(idxA, kb + half + 4);
            int j3 = __shfl(idxA, kb + half + 6);
            float v0 = hBs[(size_t)j0 * 32 + f];
            float v1 = hBs[(size_t)j1 * 32 + f];
            float v2 = hBs[(size_t)j2 * 32 + f];
            float v3 = hBs[(size_t)j3 * 32 + f];
            a += v0 + v1 + v2 + v3;
        }
        for (int k = kb + half; k < c; k += 2)     // tail: direct loads, no cross-lane
            a += hBs[(size_t)lst[k] * 32 + f];
        a += __shfl_xor(a, 32);                    // combine halves
        float di = dinv[i];
        float t = (a + hBs[(size_t)i * 32 + f]) * di;   // + self (identity term)
        float part = 0.f;
        int fbase = half * 16;
        #pragma unroll
        for (int kk = 0; kk < 16; ++kk)
            part += __shfl(t, fbase + kk) * W1[(fbase + kk) * 32 + f];
        part += __shfl_xor(part, 32);
        if (lane < 32) {
            float sv = b1[f] + part;
            h2[(size_t)i * 32 + f] = sv;
            ps = sv; pq = sv * sv;
        }
    }
    __shared__ float ls[256], lq[256];
    ls[tid] = ps; lq[tid] = pq;
    __syncthreads();
    if (tid < 32) {
        float s = 0.f, q = 0.f;
        #pragma unroll
        for (int k = 0; k < 8; ++k) { s += ls[k * 32 + tid]; q += lq[k * 32 + tid]; }
        int shard = blockIdx.x & (SHARDS - 1);
        atomicAdd(&acc[(2 * 32 + tid) * SHARDS + shard], s);
        atomicAdd(&acc[(3 * 32 + tid) * SHARDS + shard], q);
    }
}

// ---------------- K6: BN2 affine + ReLU + residual + heads ----------------
__global__ void __launch_bounds__(256) final_fused(const float* __restrict__ hB,
                                                   const float* __restrict__ h2,
                                                   const float* __restrict__ acc,
                                                   const float* __restrict__ g1,
                                                   const float* __restrict__ be1,
                                                   const float* __restrict__ Wo,
                                                   const float* __restrict__ bo,
                                                   const float* __restrict__ Wa,
                                                   const float* __restrict__ ba,
                                                   float* __restrict__ out) {
    __shared__ float sc2[32], sh2[32];
    int tid = threadIdx.x;
    if (tid < 32) {
        float S = 0.f, Q = 0.f;
        #pragma unroll
        for (int s2 = 0; s2 < SHARDS; ++s2) {
            S += acc[(2 * 32 + tid) * SHARDS + s2];
            Q += acc[(3 * 32 + tid) * SHARDS + s2];
        }
        float mu = S / (float)N_NODES;
        float var = Q / (float)N_NODES - mu * mu;
        float rstd = rsqrtf(var + BN_EPS);
        float scale = g1[tid] * rstd;
        sc2[tid] = scale; sh2[tid] = be1[tid] - mu * scale;
    }
    __syncthreads();
    const int l = tid & 31;
    int r = (blockIdx.x * 256 + tid) >> 5;         // 1250 blocks: exactly one row/group
    if (r < N_NODES) {
        int idx = r * 32 + l;
        float v = hB[idx] + fmaxf(h2[idx] * sc2[l] + sh2[l], 0.f);  // residual + h_new
        float q0 = v * Wo[l * 2 + 0];
        float q1 = v * Wo[l * 2 + 1];
        float qa = v * Wa[l];
        #pragma unroll
        for (int off = 16; off; off >>= 1) {
            q0 += __shfl_xor(q0, off);
            q1 += __shfl_xor(q1, off);
            qa += __shfl_xor(qa, off);
        }
        if (l == 0) {
            out[(size_t)r * 2 + 0] = q0 + bo[0];
            out[(size_t)r * 2 + 1] = q1 + bo[1];
            out[2 * N_NODES + r] = 1.f / (1.f + expf(-(qa + ba[0])));
        }
    }
}

extern "C" void kernel_launch(void* const* d_in, const int* in_sizes, int n_in,
                              void* d_out, int out_size, void* d_ws, size_t ws_size,
                              hipStream_t stream) {
    const float* x   = (const float*)d_in[0];
    const int*  eidx = (const int*)d_in[1];
    const int E = in_sizes[1] / 2;
    const float* W0 = (const float*)d_in[2];
    const float* b0 = (const float*)d_in[3];
    const float* g0 = (const float*)d_in[4];
    const float* be0= (const float*)d_in[5];
    const float* W1 = (const float*)d_in[6];
    const float* b1 = (const float*)d_in[7];
    const float* g1 = (const float*)d_in[8];
    const float* be1= (const float*)d_in[9];
    const float* Wo = (const float*)d_in[10];
    const float* bo = (const float*)d_in[11];
    const float* Wa = (const float*)d_in[12];
    const float* ba = (const float*)d_in[13];
    float* out = (float*)d_out;

    char* ws = (char*)d_ws;
    size_t off = 0;
    auto take = [&](size_t bytes) { char* q = ws + off; off += (bytes + 255) & ~(size_t)255; return q; };
    // bm, cnt, acc contiguous so ONE clear kernel covers all three (pads included)
    unsigned* bm  = (unsigned*)take((size_t)N_NODES * WPR * 4);    // 12,800,000 B
    int* cnt      = (int*)take((size_t)N_NODES * 4);               // 40,192 B padded
    float* acc    = (float*)take((size_t)4 * 32 * SHARDS * 4);     // 16,384 B
    const size_t clear_bytes = (size_t)N_NODES * WPR * 4 + 40192 + 16384;  // 12,856,576
    int* nbr      = (int*)take((size_t)N_NODES * CAP * 4);         // 3.84 MB
    float* dinv   = (float*)take((size_t)N_NODES * 4);
    float* h1     = (float*)take((size_t)N_NODES * 32 * 4);        // layer-1 pre-BN
    float* hB     = (float*)take((size_t)N_NODES * 32 * 4);        // post-BN1 (residual)
    float* hBs    = (float*)take((size_t)N_NODES * 32 * 4);        // dinv-prescaled
    float* h2     = (float*)take((size_t)N_NODES * 32 * 4);        // layer-2 pre-BN

    const int n16 = (int)(clear_bytes / 16);                       // 803,536
    clear_ws<<<(n16 + 255) / 256, 256, 0, stream>>>((uint4*)bm, n16);
    scatter_csr<<<(E + 255) / 256, 256, 0, stream>>>(eidx, E, bm, cnt, nbr);
    agg1_gemm_bn<<<2500, 256, 0, stream>>>(nbr, cnt, x, W0, b0, dinv, h1, acc);
    bn1_apply<<<640, 256, 0, stream>>>(h1, acc, g0, be0, dinv, hB, hBs);
    agg2_gemm_bn<<<2500, 256, 0, stream>>>(nbr, cnt, dinv, hBs, W1, b1, h2, acc);
    final_fused<<<1250, 256, 0, stream>>>(hB, h2, acc, g1, be1, Wo, bo, Wa, ba, out);
}